// Round 7
// baseline (558.090 us; speedup 1.0000x reference)
//
#include <hip/hip_runtime.h>
#include <hip/hip_bf16.h>
#include <math.h>

// LurieNet: X_{t+1} = X_t + h*(A X_t + B tanh(C X_t + by) + bx), 511 steps,
// state (128 x 512 batch), output (512, 512, 128) fp32.
// Reformulated with Y := C X + by as state:  S = [X; Y] (256 x 512),
//   V = [X_fp16; tanh(Y)_fp16],  S += h*(M V) + h*b2,  M = [[A,B],[CA,CB]].
// R7 structure: TWO launches (saves ~3 launch gaps ~70us vs R6's five):
//   k_setup (21 blocks x 1024): staged pipeline, device-scope flag handshakes
//     (R4-validated; R4's regression was a misaligned LDS pad, fixed):
//       L0 b0-4 : expm(skew(Z)) x5 (Taylor-12, bf16 hi/lo MFMA)   -> f0
//       L1 b0-2 : A, B, C (128^3 hi/lo)             (wait f0==5)  -> f1
//       L2 b3-9 : CA, CB, Y0 x4, cbx                (wait f1==3)  -> f2
//       L3 b10-20: pack M-frags(fp16)/S0/hb2        (wait f2==7)
//   k_main (32 blocks x 512): 511-step loop, fp16 single-product MFMA,
//     unrolled x2 (compile-time V buffer pointers), t=0 out in prologue.
// Encoded lessons: LDS pads must keep 16B alignment (R4); Vb stride 264
//   (2-way bank aliasing is free, best row-major can do — R5); 8 waves
//   (2/SIMD) needed for latency hiding (R5); fp16 single product both faster
//   and more accurate than bf16 hi/lo (R6); raw lgkm-only barrier (R1).

typedef __attribute__((ext_vector_type(8))) short short8;
typedef __attribute__((ext_vector_type(8))) _Float16 half8;
typedef __attribute__((ext_vector_type(4))) float f32x4;

// workspace layout (float units)
#define OFF_UO   0            // 5 * 16384 : UA_o, UB_o, VB_o, UC_o, VC_o
#define OFF_A    81920
#define OFF_B    98304
#define OFF_C    114688
#define OFF_CA   131072
#define OFF_CB   147456
#define OFF_Y0   163840       // 128 x 512
#define OFF_CBX  229376       // 128
#define OFF_HBP  229504       // 16*64*4
#define OFF_S0P  233600       // 256*512
#define OFF_MF   364672       // ushort area: M frags (fp16)

__device__ __forceinline__ unsigned short f2bf(float x){
  unsigned int u = __float_as_uint(x);
  unsigned int r = u + 0x7FFFu + ((u >> 16) & 1u);   // RNE
  return (unsigned short)(r >> 16);
}
__device__ __forceinline__ float bf2f(unsigned short b){
  return __uint_as_float(((unsigned int)b) << 16);
}
__device__ __forceinline__ void split_bf(float x, unsigned short& h, unsigned short& l){
  h = f2bf(x);
  l = f2bf(x - bf2f(h));
}
// v_cvt_pk_bf16_f32 path (RNE): low16 = bf(a), high16 = bf(b)
__device__ __forceinline__ unsigned int pk2(float a, float b){
  union { __hip_bfloat162 h; unsigned int u; } cv;
  cv.h = __float22bfloat162_rn(make_float2(a, b));
  return cv.u;
}
__device__ __forceinline__ void split2(float x0, float x1,
                                       unsigned int& hu, unsigned int& lu){
  hu = pk2(x0, x1);
  float r0 = x0 - __uint_as_float((hu & 0xFFFFu) << 16);
  float r1 = x1 - __uint_as_float(hu & 0xFFFF0000u);
  lu = pk2(r0, r1);
}
// fp16 RNE convert, bit view
__device__ __forceinline__ unsigned short f2h(float x){
  union { _Float16 f; unsigned short u; } v;
  v.f = (_Float16)x;
  return v.u;
}
__device__ __forceinline__ f32x4 mfma16(short8 a, short8 b, f32x4 c){
  return __builtin_amdgcn_mfma_f32_16x16x32_bf16(a, b, c, 0, 0, 0);
}
__device__ __forceinline__ f32x4 mfmah(half8 a, half8 b, f32x4 c){
  return __builtin_amdgcn_mfma_f32_16x16x32_f16(a, b, c, 0, 0, 0);
}
// Branchless tanh: 1 - 2/(exp(2y)+1). v_exp + v_rcp, no divergence.
__device__ __forceinline__ float tanh_fast(float y){
  float e = __expf(2.f * y);
  return 1.f - 2.f * __builtin_amdgcn_rcpf(e + 1.f);
}

// ---- device-scope handshake (R4-validated pattern) ----
__device__ __forceinline__ void bump_flag(unsigned int* f){
  __threadfence();                 // release prior global stores
  __syncthreads();
  if (threadIdx.x == 0) atomicAdd(f, 1u);
}
__device__ __forceinline__ void wait_flag(unsigned int* f, unsigned int tgt){
  if (threadIdx.x == 0){
    while (atomicAdd(f, 0u) < tgt) __builtin_amdgcn_s_sleep(8);
  }
  __syncthreads();
  __threadfence();                 // acquire producers' stores
}

// ---------------- L0: expm(skew(Z)) via Taylor-12 Horner, hi/lo bf16 MFMA
__device__ void expm_body(const float* __restrict__ Z, float* __restrict__ Eo)
{
  __shared__ unsigned short Hh[2][128][136];  // H^T (n-major), bf16 hi
  __shared__ unsigned short Hl[2][128][136];  // bf16 lo

  const int tid = threadIdx.x, lane = tid & 63, w = tid >> 6;
  const int q = lane >> 4, m16 = lane & 15;
  const int rt = w >> 2, cp = w & 3;

  short8 Rh[2][4], Rl[2][4];
  #pragma unroll
  for (int rr=0; rr<2; ++rr){
    const int row = rt*32 + rr*16 + m16;
    #pragma unroll
    for (int c=0; c<4; ++c){
      short8 hh, ll;
      #pragma unroll
      for (int j=0; j<8; ++j){
        const int k = c*32 + q*8 + j;
        float z = 0.f;
        if (row < k)      z =  Z[row*128 + k];
        else if (row > k) z = -Z[k*128 + row];
        unsigned short hb_, lb_;
        split_bf(z, hb_, lb_);
        hh[j] = (short)hb_; ll[j] = (short)lb_;
      }
      Rh[rr][c] = hh; Rl[rr][c] = ll;
    }
  }
  { // H = I into buffer 0
    unsigned short* hp = &Hh[0][0][0];
    unsigned short* lp = &Hl[0][0][0];
    for (int idx = tid; idx < 128*136; idx += 1024){
      const int n = idx / 136, k = idx - n*136;
      hp[idx] = (n == k) ? (unsigned short)0x3F80u : (unsigned short)0u;
      lp[idx] = 0u;
    }
  }
  __syncthreads();

  int cur = 0;
  for (int j = 12; j >= 1; --j){          // H = I + (R*H)/j
    const float rj = 1.f / (float)j;
    f32x4 acc[2][2];
    #pragma unroll
    for (int rr=0; rr<2; ++rr)
      #pragma unroll
      for (int cc=0; cc<2; ++cc) acc[rr][cc] = (f32x4){0.f,0.f,0.f,0.f};

    #pragma unroll
    for (int cc=0; cc<2; ++cc){
      const int n = cp*32 + cc*16 + m16;
      #pragma unroll
      for (int c=0; c<4; ++c){
        const short8 bh = *(const short8*)&Hh[cur][n][c*32 + q*8];
        const short8 bl = *(const short8*)&Hl[cur][n][c*32 + q*8];
        #pragma unroll
        for (int rr=0; rr<2; ++rr){
          acc[rr][cc] = mfma16(Rh[rr][c], bh, acc[rr][cc]);
          acc[rr][cc] = mfma16(Rl[rr][c], bh, acc[rr][cc]);
          acc[rr][cc] = mfma16(Rh[rr][c], bl, acc[rr][cc]);
        }
      }
    }
    if (j > 1){
      const int nxt = cur ^ 1;
      #pragma unroll
      for (int rr=0; rr<2; ++rr){
        #pragma unroll
        for (int cc=0; cc<2; ++cc){
          const int cg  = cp*32 + cc*16 + m16;
          const int rg0 = rt*32 + rr*16 + q*4;
          float x0 = acc[rr][cc][0]*rj + ((rg0+0)==cg ? 1.f : 0.f);
          float x1 = acc[rr][cc][1]*rj + ((rg0+1)==cg ? 1.f : 0.f);
          float x2 = acc[rr][cc][2]*rj + ((rg0+2)==cg ? 1.f : 0.f);
          float x3 = acc[rr][cc][3]*rj + ((rg0+3)==cg ? 1.f : 0.f);
          unsigned int h0,l0,h1,l1;
          split2(x0, x1, h0, l0);
          split2(x2, x3, h1, l1);
          *(uint2*)&Hh[nxt][cg][rg0] = make_uint2(h0, h1);
          *(uint2*)&Hl[nxt][cg][rg0] = make_uint2(l0, l1);
        }
      }
      __syncthreads();
      cur = nxt;
    } else {
      #pragma unroll
      for (int rr=0; rr<2; ++rr){
        #pragma unroll
        for (int cc=0; cc<2; ++cc){
          const int cg  = cp*32 + cc*16 + m16;
          const int rg0 = rt*32 + rr*16 + q*4;
          #pragma unroll
          for (int i=0; i<4; ++i)
            Eo[(rg0+i)*128 + cg] = acc[rr][cc][i] + ((rg0+i)==cg ? 1.f : 0.f);
        }
      }
    }
  }
}

// ---------------- L1: A / B / C  (one 128^3 matmul each, hi/lo 3-product)
__device__ void abc_body(int mat, float* __restrict__ ws,
    const float* __restrict__ SBm, const float* __restrict__ SCm,
    const float* __restrict__ GA1, const float* __restrict__ GAk,
    const float* __restrict__ GAp, const float* __restrict__ YA)
{
  __shared__ float dvec[128];
  __shared__ float scal[4];
  __shared__ float sb[128], sc[128];
  const int tid = threadIdx.x;

  const float* U; const float* V; float* Out;
  if (mat == 0){ U = ws + OFF_UO;          V = U;                    Out = ws + OFF_A; }
  else if (mat == 1){ U = ws + OFF_UO + 16384; V = ws + OFF_UO + 32768; Out = ws + OFF_B; }
  else { U = ws + OFF_UO + 49152; V = ws + OFF_UO + 65536; Out = ws + OFF_C; }

  if (mat == 0){
    if (tid < 128){ sb[tid] = fabsf(SBm[tid*129]); sc[tid] = fabsf(SCm[tid*129]); }
    __syncthreads();
    if (tid == 0){
      float b1=0.f,b2=0.f,c1=0.f,c2=0.f;
      for (int i=0;i<128;++i){
        float vb = sb[i];
        if (vb > b1){ b2=b1; b1=vb; } else if (vb > b2) b2=vb;
        float vc = sc[i];
        if (vc > c1){ c2=c1; c1=vc; } else if (vc > c2) c2=vc;
      }
      float alpha = sqrtf(8.f*(b1*b1*c1*c1 + b2*b2*c2*c2));  // 4*K*G^2 = 8
      float sa0 = GA1[0];
      float sa2 = -(alpha + sa0) - (fabsf(GAk[0]) + 1e-5f);
      float mm  = fminf(fminf(sa0, sa2), 0.f);
      scal[0]=sa0; scal[1]=sa2; scal[2]=mm;
    }
    __syncthreads();
    if (tid < 128){
      float v;
      if (tid == 0) v = scal[0];
      else if (tid == 1) v = scal[1];
      else v = scal[2] - fabsf(GAp[(tid-2)*127]);  // diag of (126x126)
      dvec[tid] = v;
    }
  } else {
    const float* Sm = (mat == 1) ? SBm : SCm;
    if (tid < 128) dvec[tid] = fabsf(Sm[tid*129]);
  }
  __syncthreads();

  const int lane = tid & 63, w = tid >> 6, q = lane >> 4, m16 = lane & 15;
  const int rt = w >> 2, cp = w & 3;

  short8 Ah[2][4], Al[2][4];
  #pragma unroll
  for (int rr=0; rr<2; ++rr){
    const int row = rt*32 + rr*16 + m16;
    #pragma unroll
    for (int c=0; c<4; ++c){
      const float* up = U + row*128 + c*32 + q*8;
      const f32x4 u0 = *(const f32x4*)up;
      const f32x4 u1 = *(const f32x4*)(up + 4);
      short8 hh, ll;
      #pragma unroll
      for (int jj=0; jj<4; ++jj){
        unsigned short hb_, lb_;
        split_bf(u0[jj], hb_, lb_); hh[jj]   = (short)hb_; ll[jj]   = (short)lb_;
        split_bf(u1[jj], hb_, lb_); hh[jj+4] = (short)hb_; ll[jj+4] = (short)lb_;
      }
      Ah[rr][c] = hh; Al[rr][c] = ll;
    }
  }
  f32x4 acc[2][2];
  #pragma unroll
  for (int rr=0; rr<2; ++rr)
    #pragma unroll
    for (int cc=0; cc<2; ++cc) acc[rr][cc] = (f32x4){0.f,0.f,0.f,0.f};

  #pragma unroll
  for (int cc=0; cc<2; ++cc){
    const int n = cp*32 + cc*16 + m16;
    #pragma unroll
    for (int c=0; c<4; ++c){
      const int k0 = c*32 + q*8;
      const float* vp = V + n*128 + k0;            // B[k][n] = dvec[k]*V[n][k]
      const f32x4 v0 = *(const f32x4*)vp;
      const f32x4 v1 = *(const f32x4*)(vp + 4);
      short8 bh, bl;
      #pragma unroll
      for (int jj=0; jj<4; ++jj){
        unsigned short hb_, lb_;
        split_bf(v0[jj]*dvec[k0+jj],   hb_, lb_); bh[jj]   = (short)hb_; bl[jj]   = (short)lb_;
        split_bf(v1[jj]*dvec[k0+4+jj], hb_, lb_); bh[jj+4] = (short)hb_; bl[jj+4] = (short)lb_;
      }
      #pragma unroll
      for (int rr=0; rr<2; ++rr){
        acc[rr][cc] = mfma16(Ah[rr][c], bh, acc[rr][cc]);
        acc[rr][cc] = mfma16(Al[rr][c], bh, acc[rr][cc]);
        acc[rr][cc] = mfma16(Ah[rr][c], bl, acc[rr][cc]);
      }
    }
  }
  #pragma unroll
  for (int rr=0; rr<2; ++rr){
    #pragma unroll
    for (int cc=0; cc<2; ++cc){
      const int cg  = cp*32 + cc*16 + m16;
      const int rg0 = rt*32 + rr*16 + q*4;
      #pragma unroll
      for (int i=0; i<4; ++i){
        float x = acc[rr][cc][i];
        if (mat == 0){
          const int r = rg0 + i;
          float sk = 0.f;
          if (r < cg) sk = YA[r*128 + cg];
          else if (r > cg) sk = -YA[cg*128 + r];
          x = 0.5f*x + 0.5f*sk;
        }
        Out[(rg0+i)*128 + cg] = x;
      }
    }
  }
}

// shared helper: load C row-fragments (A-operand)
__device__ __forceinline__ void c_rowfrags(const float* __restrict__ Cm,
    int rt, int m16, int q, short8 (*Ah)[4], short8 (*Al)[4])
{
  #pragma unroll
  for (int rr=0; rr<2; ++rr){
    const int row = rt*32 + rr*16 + m16;
    #pragma unroll
    for (int c=0; c<4; ++c){
      const float* up = Cm + row*128 + c*32 + q*8;
      const f32x4 u0 = *(const f32x4*)up;
      const f32x4 u1 = *(const f32x4*)(up + 4);
      short8 hh, ll;
      #pragma unroll
      for (int jj=0; jj<4; ++jj){
        unsigned short hb_, lb_;
        split_bf(u0[jj], hb_, lb_); hh[jj]   = (short)hb_; ll[jj]   = (short)lb_;
        split_bf(u1[jj], hb_, lb_); hh[jj+4] = (short)hb_; ll[jj+4] = (short)lb_;
      }
      Ah[rr][c] = hh; Al[rr][c] = ll;
    }
  }
}

// ---------------- L2: CA / CB
__device__ void cacb_body(int role, float* __restrict__ ws)
{
  const int tid = threadIdx.x;
  const int lane = tid & 63, w = tid >> 6, q = lane >> 4, m16 = lane & 15;
  const int rt = w >> 2, cp = w & 3;
  const float* Cm = ws + OFF_C;

  short8 Ah[2][4], Al[2][4];
  c_rowfrags(Cm, rt, m16, q, Ah, Al);

  f32x4 acc[2][2];
  #pragma unroll
  for (int rr=0; rr<2; ++rr)
    #pragma unroll
    for (int cc=0; cc<2; ++cc) acc[rr][cc] = (f32x4){0.f,0.f,0.f,0.f};

  const float* Rm = ws + ((role == 0) ? OFF_A : OFF_B);
  #pragma unroll
  for (int cc=0; cc<2; ++cc){
    const int n = cp*32 + cc*16 + m16;
    #pragma unroll
    for (int c=0; c<4; ++c){
      const int k0 = c*32 + q*8;
      short8 bh, bl;
      #pragma unroll
      for (int jj=0; jj<8; ++jj){
        unsigned short hb_, lb_;
        split_bf(Rm[(k0+jj)*128 + n], hb_, lb_);
        bh[jj] = (short)hb_; bl[jj] = (short)lb_;
      }
      #pragma unroll
      for (int rr=0; rr<2; ++rr){
        acc[rr][cc] = mfma16(Ah[rr][c], bh, acc[rr][cc]);
        acc[rr][cc] = mfma16(Al[rr][c], bh, acc[rr][cc]);
        acc[rr][cc] = mfma16(Ah[rr][c], bl, acc[rr][cc]);
      }
    }
  }
  float* Om = ws + ((role == 0) ? OFF_CA : OFF_CB);
  #pragma unroll
  for (int rr=0; rr<2; ++rr){
    #pragma unroll
    for (int cc=0; cc<2; ++cc){
      const int cg  = cp*32 + cc*16 + m16;
      const int rg0 = rt*32 + rr*16 + q*4;
      #pragma unroll
      for (int i=0; i<4; ++i) Om[(rg0+i)*128 + cg] = acc[rr][cc][i];
    }
  }
}

// ---------------- L2: Y0 panel = C X0^T + by  (128 batch cols per panel)
__device__ void y0_body(int panel, float* __restrict__ ws,
    const float* __restrict__ X0, const float* __restrict__ by)
{
  const int tid = threadIdx.x;
  const int lane = tid & 63, w = tid >> 6, q = lane >> 4, m16 = lane & 15;
  const int rt = w >> 2, cp = w & 3;
  const float* Cm = ws + OFF_C;

  short8 Ah[2][4], Al[2][4];
  c_rowfrags(Cm, rt, m16, q, Ah, Al);

  f32x4 acc[2][2];
  #pragma unroll
  for (int rr=0; rr<2; ++rr)
    #pragma unroll
    for (int cc=0; cc<2; ++cc) acc[rr][cc] = (f32x4){0.f,0.f,0.f,0.f};

  const int bcolbase = panel * 128;
  #pragma unroll
  for (int cc=0; cc<2; ++cc){
    const int bcol = bcolbase + cp*32 + cc*16 + m16;
    #pragma unroll
    for (int c=0; c<4; ++c){
      const int k0 = c*32 + q*8;
      const float* xp = X0 + bcol*128 + k0;      // B[k][b] = X0[b][k]
      const f32x4 x0v = *(const f32x4*)xp;
      const f32x4 x1v = *(const f32x4*)(xp + 4);
      short8 bh, bl;
      #pragma unroll
      for (int jj=0; jj<4; ++jj){
        unsigned short hb_, lb_;
        split_bf(x0v[jj], hb_, lb_); bh[jj]   = (short)hb_; bl[jj]   = (short)lb_;
        split_bf(x1v[jj], hb_, lb_); bh[jj+4] = (short)hb_; bl[jj+4] = (short)lb_;
      }
      #pragma unroll
      for (int rr=0; rr<2; ++rr){
        acc[rr][cc] = mfma16(Ah[rr][c], bh, acc[rr][cc]);
        acc[rr][cc] = mfma16(Al[rr][c], bh, acc[rr][cc]);
        acc[rr][cc] = mfma16(Ah[rr][c], bl, acc[rr][cc]);
      }
    }
  }
  float* Y0p = ws + OFF_Y0;
  #pragma unroll
  for (int rr=0; rr<2; ++rr){
    #pragma unroll
    for (int cc=0; cc<2; ++cc){
      const int bcol = bcolbase + cp*32 + cc*16 + m16;
      const int rg0  = rt*32 + rr*16 + q*4;
      #pragma unroll
      for (int i=0; i<4; ++i)
        Y0p[(rg0+i)*512 + bcol] = acc[rr][cc][i] + by[rg0+i];
    }
  }
}

// ---------------- L2: cbx = C @ bx
__device__ void cbx_body(float* __restrict__ ws, const float* __restrict__ bx)
{
  __shared__ float bxs[128];
  const int tid = threadIdx.x;
  if (tid < 128) bxs[tid] = bx[tid];
  __syncthreads();
  const int r = tid >> 3, p = tid & 7;
  const float* cr = ws + OFF_C + r*128 + p*16;
  float s = 0.f;
  #pragma unroll
  for (int j=0; j<16; ++j) s += cr[j]*bxs[p*16+j];
  s += __shfl_xor(s, 1); s += __shfl_xor(s, 2); s += __shfl_xor(s, 4);
  if (p == 0) ws[OFF_CBX + r] = s;
}

// ---------------- L3: pack M fragments (fp16), S0, h*b2 (11 blocks)
__device__ void pack_body(int pb, float* __restrict__ ws,
    const float* __restrict__ X0, const float* __restrict__ bx)
{
  unsigned short* Mf = (unsigned short*)(ws + OFF_MF);
  for (int fid = pb*1024 + threadIdx.x; fid < 41984; fid += 11*1024){
    if (fid < 8192){               // M frags: tile w(16 rows), chunk c, lane l
      const int w = fid >> 9, c = (fid >> 6) & 7, l = fid & 63;
      const int q = l >> 4, m16 = l & 15;
      const int row = w*16 + m16;            // 0..255 of M = [[A,B],[CA,CB]]
      const int k0 = c*32 + q*8;             // 0..255
      const float* src;
      if (row < 128) src = (k0 < 128) ? (ws + OFF_A  + row*128 + k0)
                                      : (ws + OFF_B  + row*128 + (k0-128));
      else           src = (k0 < 128) ? (ws + OFF_CA + (row-128)*128 + k0)
                                      : (ws + OFF_CB + (row-128)*128 + (k0-128));
      unsigned short* dh = Mf + (size_t)w*8192 + c*1024 + l*8;
      #pragma unroll
      for (int j=0; j<8; ++j) dh[j] = f2h(src[j]);   // fp16 RNE
    } else if (fid < 40960){       // S0 packed per (wg, tile, lane)
      const int t = fid - 8192;
      const int wg = t >> 10, w = (t >> 6) & 15, l = t & 63;
      const int q = l >> 4, m16 = l & 15;
      const int col = wg*16 + m16;
      const int r0 = w*16 + q*4;
      f32x4 v;
      if (r0 < 128){
        v = *(const f32x4*)(X0 + col*128 + r0);
      } else {
        const float* Y0p = ws + OFF_Y0;
        v[0] = Y0p[(r0-128)*512 + col]; v[1] = Y0p[(r0-127)*512 + col];
        v[2] = Y0p[(r0-126)*512 + col]; v[3] = Y0p[(r0-125)*512 + col];
      }
      *(f32x4*)(ws + OFF_S0P + (size_t)t*4) = v;
    } else {                       // h*b2 packed per (tile, lane)
      const int t2 = fid - 40960;
      const int w = t2 >> 6, l = t2 & 63, q = l >> 4;
      const int r0 = w*16 + q*4;
      f32x4 v;
      #pragma unroll
      for (int i=0; i<4; ++i){
        const int r = r0 + i;
        v[i] = 0.01f * ((r < 128) ? bx[r] : ws[OFF_CBX + (r-128)]);
      }
      *(f32x4*)(ws + OFF_HBP + (size_t)t2*4) = v;
    }
  }
}

// ---------------- K1: staged setup pipeline, one launch
__global__ __launch_bounds__(1024) void k_setup(
    const float* __restrict__ UA, const float* __restrict__ UB,
    const float* __restrict__ VB, const float* __restrict__ UC,
    const float* __restrict__ VC, float* __restrict__ ws,
    const float* __restrict__ SBm, const float* __restrict__ SCm,
    const float* __restrict__ GA1, const float* __restrict__ GAk,
    const float* __restrict__ GAp, const float* __restrict__ YA,
    const float* __restrict__ X0, const float* __restrict__ bx,
    const float* __restrict__ by, unsigned int* __restrict__ flags)
{
  const int b = blockIdx.x;
  unsigned int* f0 = flags + 0;
  unsigned int* f1 = flags + 1;
  unsigned int* f2 = flags + 2;

  if (b < 5){                      // L0: expm
    const float* Z = (b==0)?UA:((b==1)?UB:((b==2)?VB:((b==3)?UC:VC)));
    expm_body(Z, ws + OFF_UO + b*16384);
    bump_flag(f0);
  }
  if (b < 3){                      // L1: A, B, C
    wait_flag(f0, 5u);
    abc_body(b, ws, SBm, SCm, GA1, GAk, GAp, YA);
    bump_flag(f1);
    return;
  }
  if (b < 5){                      // L2: CA, CB
    wait_flag(f1, 3u);
    cacb_body(b - 3, ws);
    bump_flag(f2);
    return;
  }
  if (b < 9){                      // L2: Y0 panels
    wait_flag(f1, 3u);
    y0_body(b - 5, ws, X0, by);
    bump_flag(f2);
    return;
  }
  if (b == 9){                     // L2: cbx
    wait_flag(f1, 3u);
    cbx_body(ws, bx);
    bump_flag(f2);
    return;
  }
  // L3: pack (blocks 10..20)
  wait_flag(f2, 7u);
  pack_body(b - 10, ws, X0, bx);
}

// ---------------- K2: 511-step recurrence. 32 WGs x 512 thr (8 waves, 2/SIMD).
// Each wave owns 16 X rows (tile w) AND 16 Y rows (tile 8+w): symmetric waves.
// SINGLE fp16 MFMA per (tile, chunk): 16 MFMAs/wave/step. Even/odd chunk
// accumulator pairs for ILP. Y MFMAs first (Y finish overlaps X MFMAs).
// Raw barrier with lgkm-only drain; global stores ride across steps.
// Loop unrolled x2 so V buffer pointers are compile-time constant.
__global__ __launch_bounds__(512) void k_main(const float* __restrict__ ws,
                                              float* __restrict__ out)
{
  const unsigned short* Mf = (const unsigned short*)(ws + OFF_MF);
  const float* S0p = ws + OFF_S0P;
  const float* hbp = ws + OFF_HBP;

  __shared__ unsigned short Vb[2][16][264];  // V^T (fp16): [buf][col n][row k]

  const int tid = threadIdx.x, lane = tid & 63, w = tid >> 6, wg = blockIdx.x;
  const int q = lane >> 4, m16 = lane & 15;

  // r2=0 -> X tile w (rows 16w..16w+15), r2=1 -> Y tile 8+w
  half8 Mh[2][8];
  #pragma unroll
  for (int r2=0; r2<2; ++r2){
    const unsigned short* bp = Mf + (size_t)(w + 8*r2)*8192 + lane*8;
    #pragma unroll
    for (int c=0; c<8; ++c) Mh[r2][c] = *(const half8*)(bp + c*1024);
  }
  f32x4 S[2], hb[2];
  #pragma unroll
  for (int r2=0; r2<2; ++r2){
    S[r2]  = *(const f32x4*)(S0p + (size_t)((wg*16 + w + 8*r2)*64 + lane)*4);
    hb[r2] = *(const f32x4*)(hbp + (size_t)((w + 8*r2)*64 + lane)*4);
  }
  const int r0x = w*16 + q*4;           // owned X rows (V position = row)
  const int r0y = 128 + w*16 + q*4;     // owned Y rows (V position = 128+row)

  float* op = out + (size_t)(wg*16 + m16)*65536 + r0x;   // + t*128
  *(f32x4*)op = S[0];                   // t = 0 output (S0P X-part == X0)

  { // initial V = [X0_fp16 ; tanh(Y0)_fp16]
    union { _Float16 f[4]; uint2 u; } pk;
    #pragma unroll
    for (int i=0; i<4; ++i) pk.f[i] = (_Float16)S[0][i];
    *(uint2*)&Vb[0][m16][r0x] = pk.u;
    #pragma unroll
    for (int i=0; i<4; ++i) pk.f[i] = (_Float16)tanh_fast(S[1][i]);
    *(uint2*)&Vb[0][m16][r0y] = pk.u;
  }
  asm volatile("s_waitcnt lgkmcnt(0)" ::: "memory");
  __builtin_amdgcn_s_barrier();
  asm volatile("" ::: "memory");

  auto step = [&](const unsigned short (*vs)[264], unsigned short (*vd)[264],
                  int t){
    const unsigned short* vrow = &vs[m16][q*8];
    half8 vf[8];
    #pragma unroll
    for (int c=0; c<8; ++c) vf[c] = *(const half8*)(vrow + c*32);

    // Y tile first (even/odd chunk chains)...
    f32x4 e1 = (f32x4){0.f,0.f,0.f,0.f}, o1 = (f32x4){0.f,0.f,0.f,0.f};
    #pragma unroll
    for (int c=0; c<8; c+=2){
      e1 = mfmah(Mh[1][c],   vf[c],   e1);
      o1 = mfmah(Mh[1][c+1], vf[c+1], o1);
    }
    // ...X tile second; Y finish is independent of these MFMAs.
    f32x4 e0 = (f32x4){0.f,0.f,0.f,0.f}, o0 = (f32x4){0.f,0.f,0.f,0.f};
    #pragma unroll
    for (int c=0; c<8; c+=2){
      e0 = mfmah(Mh[0][c],   vf[c],   e0);
      o0 = mfmah(Mh[0][c+1], vf[c+1], o0);
    }
    { // Y finish: update, tanh, pack fp16, LDS write
      union { _Float16 f[4]; uint2 u; } pk;
      #pragma unroll
      for (int i=0; i<4; ++i){
        S[1][i] += 0.01f*(e1[i] + o1[i]) + hb[1][i];
        pk.f[i] = (_Float16)tanh_fast(S[1][i]);
      }
      *(uint2*)&vd[m16][r0y] = pk.u;
    }
    { // X finish: update, pack fp16, LDS write
      union { _Float16 f[4]; uint2 u; } pk;
      #pragma unroll
      for (int i=0; i<4; ++i){
        S[0][i] += 0.01f*(e0[i] + o0[i]) + hb[0][i];
        pk.f[i] = (_Float16)S[0][i];
      }
      *(uint2*)&vd[m16][r0x] = pk.u;
    }
    // raw barrier: drain LDS writes only; global stores stay in flight.
    asm volatile("s_waitcnt lgkmcnt(0)" ::: "memory");
    __builtin_amdgcn_s_barrier();
    asm volatile("" ::: "memory");
    // X fp32 store after the barrier: overlaps next step's LDS reads/MFMAs.
    *(f32x4*)(op + (size_t)t*128) = S[0];
  };

  for (int t = 1; t < 511; t += 2){      // 255 double-steps: buf0->1, buf1->0
    step(Vb[0], Vb[1], t);
    step(Vb[1], Vb[0], t + 1);
  }
  step(Vb[0], Vb[1], 511);               // final step
}

extern "C" void kernel_launch(void* const* d_in, const int* in_sizes, int n_in,
                              void* d_out, int out_size, void* d_ws, size_t ws_size,
                              hipStream_t stream)
{
  (void)in_sizes; (void)n_in; (void)out_size; (void)ws_size;
  const float* X0  = (const float*)d_in[0];
  const float* GA1 = (const float*)d_in[1];
  const float* GAk = (const float*)d_in[2];
  const float* GAp = (const float*)d_in[3];
  const float* YA  = (const float*)d_in[4];
  const float* UA  = (const float*)d_in[5];
  const float* UB  = (const float*)d_in[6];
  const float* VB  = (const float*)d_in[7];
  const float* SBm = (const float*)d_in[8];
  const float* UC  = (const float*)d_in[9];
  const float* VC  = (const float*)d_in[10];
  const float* SCm = (const float*)d_in[11];
  const float* bx  = (const float*)d_in[12];
  const float* by  = (const float*)d_in[13];
  float* out = (float*)d_out;
  float* ws  = (float*)d_ws;

  // flags live in out[0..3] (overwritten later by k_main's t=0 store)
  hipMemsetAsync(d_out, 0, 16, stream);
  k_setup<<<dim3(21), dim3(1024), 0, stream>>>(UA, UB, VB, UC, VC, ws,
                                               SBm, SCm, GA1, GAk, GAp, YA,
                                               X0, bx, by, (unsigned int*)d_out);
  k_main <<<dim3(32), dim3(512),  0, stream>>>(ws, out);
}

// Round 8
// 517.795 us; speedup vs baseline: 1.0778x; 1.0778x over previous
//
#include <hip/hip_runtime.h>
#include <hip/hip_bf16.h>
#include <math.h>

// LurieNet: X_{t+1} = X_t + h*(A X_t + B tanh(C X_t + by) + bx), 511 steps,
// state (128 x 512 batch), output (512, 512, 128) fp32.
// Reformulated with Y := C X + by as state:  S = [X; Y] (256 x 512),
//   V = [X_fp16; tanh(Y)_fp16],  S += h*(M V) + h*b2,  M = [[A,B],[CA,CB]].
// R8 = R6's measured-optimal 5-launch chain + R7's improved k_main.
// Launch-structure findings (closed): staged in-kernel flag pipeline is ~40us
//   WORSE than 4 dependent-dispatch gaps (R7); 1-block serial prep -180us
//   (R2); per-block redundant prep -100us (R3). Five launches win.
// k_main findings (closed): LDS read serialization (64 b128/step/CU) is the
//   dominant step term; all restructurings (fewer row-splits, k-split partial
//   sums, more blocks) pencil out neutral or worse. fp16 single product (R6)
//   + x2 unroll w/ compile-time V pointers (R7) is the floor of this design.
// Encoded lessons: LDS pads must keep 16B alignment (R4); Vb stride 264 is
//   bank-optimal for row-major (R5); 8 waves = 2/SIMD needed (R5).

typedef __attribute__((ext_vector_type(8))) short short8;
typedef __attribute__((ext_vector_type(8))) _Float16 half8;
typedef __attribute__((ext_vector_type(4))) float f32x4;

// workspace layout (float units)
#define OFF_UO   0            // 5 * 16384 : UA_o, UB_o, VB_o, UC_o, VC_o
#define OFF_A    81920
#define OFF_B    98304
#define OFF_C    114688
#define OFF_CA   131072
#define OFF_CB   147456
#define OFF_Y0   163840       // 128 x 512
#define OFF_CBX  229376       // 128
#define OFF_HBP  229504       // 16*64*4
#define OFF_S0P  233600       // 256*512
#define OFF_MF   364672       // ushort area: M frags (fp16)

__device__ __forceinline__ unsigned short f2bf(float x){
  unsigned int u = __float_as_uint(x);
  unsigned int r = u + 0x7FFFu + ((u >> 16) & 1u);   // RNE
  return (unsigned short)(r >> 16);
}
__device__ __forceinline__ float bf2f(unsigned short b){
  return __uint_as_float(((unsigned int)b) << 16);
}
__device__ __forceinline__ void split_bf(float x, unsigned short& h, unsigned short& l){
  h = f2bf(x);
  l = f2bf(x - bf2f(h));
}
// v_cvt_pk_bf16_f32 path (RNE): low16 = bf(a), high16 = bf(b)
__device__ __forceinline__ unsigned int pk2(float a, float b){
  union { __hip_bfloat162 h; unsigned int u; } cv;
  cv.h = __float22bfloat162_rn(make_float2(a, b));
  return cv.u;
}
__device__ __forceinline__ void split2(float x0, float x1,
                                       unsigned int& hu, unsigned int& lu){
  hu = pk2(x0, x1);
  float r0 = x0 - __uint_as_float((hu & 0xFFFFu) << 16);
  float r1 = x1 - __uint_as_float(hu & 0xFFFF0000u);
  lu = pk2(r0, r1);
}
// fp16 RNE convert, bit view
__device__ __forceinline__ unsigned short f2h(float x){
  union { _Float16 f; unsigned short u; } v;
  v.f = (_Float16)x;
  return v.u;
}
__device__ __forceinline__ f32x4 mfma16(short8 a, short8 b, f32x4 c){
  return __builtin_amdgcn_mfma_f32_16x16x32_bf16(a, b, c, 0, 0, 0);
}
__device__ __forceinline__ f32x4 mfmah(half8 a, half8 b, f32x4 c){
  return __builtin_amdgcn_mfma_f32_16x16x32_f16(a, b, c, 0, 0, 0);
}
// Branchless tanh: 1 - 2/(exp(2y)+1). v_exp + v_rcp, no divergence.
__device__ __forceinline__ float tanh_fast(float y){
  float e = __expf(2.f * y);
  return 1.f - 2.f * __builtin_amdgcn_rcpf(e + 1.f);
}

// ---------------- K1: 5 x expm(skew(Z)) via Taylor-12 Horner, hi/lo bf16 MFMA
__global__ __launch_bounds__(1024) void k_expm(
    const float* __restrict__ UA, const float* __restrict__ UB,
    const float* __restrict__ VB, const float* __restrict__ UC,
    const float* __restrict__ VC, float* __restrict__ ws)
{
  const int b = blockIdx.x;
  const float* Z = (b==0)?UA:((b==1)?UB:((b==2)?VB:((b==3)?UC:VC)));
  float* Eo = ws + OFF_UO + b*16384;

  __shared__ unsigned short Hh[2][128][136];  // H^T (n-major), bf16 hi
  __shared__ unsigned short Hl[2][128][136];  // bf16 lo

  const int tid = threadIdx.x, lane = tid & 63, w = tid >> 6;
  const int q = lane >> 4, m16 = lane & 15;
  const int rt = w >> 2, cp = w & 3;

  short8 Rh[2][4], Rl[2][4];
  #pragma unroll
  for (int rr=0; rr<2; ++rr){
    const int row = rt*32 + rr*16 + m16;
    #pragma unroll
    for (int c=0; c<4; ++c){
      short8 hh, ll;
      #pragma unroll
      for (int j=0; j<8; ++j){
        const int k = c*32 + q*8 + j;
        float z = 0.f;
        if (row < k)      z =  Z[row*128 + k];
        else if (row > k) z = -Z[k*128 + row];
        unsigned short hb_, lb_;
        split_bf(z, hb_, lb_);
        hh[j] = (short)hb_; ll[j] = (short)lb_;
      }
      Rh[rr][c] = hh; Rl[rr][c] = ll;
    }
  }
  { // H = I into buffer 0
    unsigned short* hp = &Hh[0][0][0];
    unsigned short* lp = &Hl[0][0][0];
    for (int idx = tid; idx < 128*136; idx += 1024){
      const int n = idx / 136, k = idx - n*136;
      hp[idx] = (n == k) ? (unsigned short)0x3F80u : (unsigned short)0u;
      lp[idx] = 0u;
    }
  }
  __syncthreads();

  int cur = 0;
  for (int j = 12; j >= 1; --j){          // H = I + (R*H)/j
    const float rj = 1.f / (float)j;
    f32x4 acc[2][2];
    #pragma unroll
    for (int rr=0; rr<2; ++rr)
      #pragma unroll
      for (int cc=0; cc<2; ++cc) acc[rr][cc] = (f32x4){0.f,0.f,0.f,0.f};

    #pragma unroll
    for (int cc=0; cc<2; ++cc){
      const int n = cp*32 + cc*16 + m16;
      #pragma unroll
      for (int c=0; c<4; ++c){
        const short8 bh = *(const short8*)&Hh[cur][n][c*32 + q*8];
        const short8 bl = *(const short8*)&Hl[cur][n][c*32 + q*8];
        #pragma unroll
        for (int rr=0; rr<2; ++rr){
          acc[rr][cc] = mfma16(Rh[rr][c], bh, acc[rr][cc]);
          acc[rr][cc] = mfma16(Rl[rr][c], bh, acc[rr][cc]);
          acc[rr][cc] = mfma16(Rh[rr][c], bl, acc[rr][cc]);
        }
      }
    }
    if (j > 1){
      const int nxt = cur ^ 1;
      #pragma unroll
      for (int rr=0; rr<2; ++rr){
        #pragma unroll
        for (int cc=0; cc<2; ++cc){
          const int cg  = cp*32 + cc*16 + m16;
          const int rg0 = rt*32 + rr*16 + q*4;
          float x0 = acc[rr][cc][0]*rj + ((rg0+0)==cg ? 1.f : 0.f);
          float x1 = acc[rr][cc][1]*rj + ((rg0+1)==cg ? 1.f : 0.f);
          float x2 = acc[rr][cc][2]*rj + ((rg0+2)==cg ? 1.f : 0.f);
          float x3 = acc[rr][cc][3]*rj + ((rg0+3)==cg ? 1.f : 0.f);
          unsigned int h0,l0,h1,l1;
          split2(x0, x1, h0, l0);
          split2(x2, x3, h1, l1);
          *(uint2*)&Hh[nxt][cg][rg0] = make_uint2(h0, h1);
          *(uint2*)&Hl[nxt][cg][rg0] = make_uint2(l0, l1);
        }
      }
      __syncthreads();
      cur = nxt;
    } else {
      #pragma unroll
      for (int rr=0; rr<2; ++rr){
        #pragma unroll
        for (int cc=0; cc<2; ++cc){
          const int cg  = cp*32 + cc*16 + m16;
          const int rg0 = rt*32 + rr*16 + q*4;
          #pragma unroll
          for (int i=0; i<4; ++i)
            Eo[(rg0+i)*128 + cg] = acc[rr][cc][i] + ((rg0+i)==cg ? 1.f : 0.f);
        }
      }
    }
  }
}

// ---------------- K3: A, B, C  (one 128^3 matmul each, hi/lo 3-product)
__global__ __launch_bounds__(1024) void k_abc(float* __restrict__ ws,
    const float* __restrict__ SBm, const float* __restrict__ SCm,
    const float* __restrict__ GA1, const float* __restrict__ GAk,
    const float* __restrict__ GAp, const float* __restrict__ YA)
{
  const int mat = blockIdx.x;   // 0=A 1=B 2=C
  __shared__ float dvec[128];
  __shared__ float scal[4];
  __shared__ float sb[128], sc[128];
  const int tid = threadIdx.x;

  const float* U; const float* V; float* Out;
  if (mat == 0){ U = ws + OFF_UO;          V = U;                    Out = ws + OFF_A; }
  else if (mat == 1){ U = ws + OFF_UO + 16384; V = ws + OFF_UO + 32768; Out = ws + OFF_B; }
  else { U = ws + OFF_UO + 49152; V = ws + OFF_UO + 65536; Out = ws + OFF_C; }

  if (mat == 0){
    if (tid < 128){ sb[tid] = fabsf(SBm[tid*129]); sc[tid] = fabsf(SCm[tid*129]); }
    __syncthreads();
    if (tid == 0){
      float b1=0.f,b2=0.f,c1=0.f,c2=0.f;
      for (int i=0;i<128;++i){
        float vb = sb[i];
        if (vb > b1){ b2=b1; b1=vb; } else if (vb > b2) b2=vb;
        float vc = sc[i];
        if (vc > c1){ c2=c1; c1=vc; } else if (vc > c2) c2=vc;
      }
      float alpha = sqrtf(8.f*(b1*b1*c1*c1 + b2*b2*c2*c2));  // 4*K*G^2 = 8
      float sa0 = GA1[0];
      float sa2 = -(alpha + sa0) - (fabsf(GAk[0]) + 1e-5f);
      float mm  = fminf(fminf(sa0, sa2), 0.f);
      scal[0]=sa0; scal[1]=sa2; scal[2]=mm;
    }
    __syncthreads();
    if (tid < 128){
      float v;
      if (tid == 0) v = scal[0];
      else if (tid == 1) v = scal[1];
      else v = scal[2] - fabsf(GAp[(tid-2)*127]);  // diag of (126x126)
      dvec[tid] = v;
    }
  } else {
    const float* Sm = (mat == 1) ? SBm : SCm;
    if (tid < 128) dvec[tid] = fabsf(Sm[tid*129]);
  }
  __syncthreads();

  const int lane = tid & 63, w = tid >> 6, q = lane >> 4, m16 = lane & 15;
  const int rt = w >> 2, cp = w & 3;

  short8 Ah[2][4], Al[2][4];
  #pragma unroll
  for (int rr=0; rr<2; ++rr){
    const int row = rt*32 + rr*16 + m16;
    #pragma unroll
    for (int c=0; c<4; ++c){
      const float* up = U + row*128 + c*32 + q*8;
      const f32x4 u0 = *(const f32x4*)up;
      const f32x4 u1 = *(const f32x4*)(up + 4);
      short8 hh, ll;
      #pragma unroll
      for (int jj=0; jj<4; ++jj){
        unsigned short hb_, lb_;
        split_bf(u0[jj], hb_, lb_); hh[jj]   = (short)hb_; ll[jj]   = (short)lb_;
        split_bf(u1[jj], hb_, lb_); hh[jj+4] = (short)hb_; ll[jj+4] = (short)lb_;
      }
      Ah[rr][c] = hh; Al[rr][c] = ll;
    }
  }
  f32x4 acc[2][2];
  #pragma unroll
  for (int rr=0; rr<2; ++rr)
    #pragma unroll
    for (int cc=0; cc<2; ++cc) acc[rr][cc] = (f32x4){0.f,0.f,0.f,0.f};

  #pragma unroll
  for (int cc=0; cc<2; ++cc){
    const int n = cp*32 + cc*16 + m16;
    #pragma unroll
    for (int c=0; c<4; ++c){
      const int k0 = c*32 + q*8;
      const float* vp = V + n*128 + k0;            // B[k][n] = dvec[k]*V[n][k]
      const f32x4 v0 = *(const f32x4*)vp;
      const f32x4 v1 = *(const f32x4*)(vp + 4);
      short8 bh, bl;
      #pragma unroll
      for (int jj=0; jj<4; ++jj){
        unsigned short hb_, lb_;
        split_bf(v0[jj]*dvec[k0+jj],   hb_, lb_); bh[jj]   = (short)hb_; bl[jj]   = (short)lb_;
        split_bf(v1[jj]*dvec[k0+4+jj], hb_, lb_); bh[jj+4] = (short)hb_; bl[jj+4] = (short)lb_;
      }
      #pragma unroll
      for (int rr=0; rr<2; ++rr){
        acc[rr][cc] = mfma16(Ah[rr][c], bh, acc[rr][cc]);
        acc[rr][cc] = mfma16(Al[rr][c], bh, acc[rr][cc]);
        acc[rr][cc] = mfma16(Ah[rr][c], bl, acc[rr][cc]);
      }
    }
  }
  #pragma unroll
  for (int rr=0; rr<2; ++rr){
    #pragma unroll
    for (int cc=0; cc<2; ++cc){
      const int cg  = cp*32 + cc*16 + m16;
      const int rg0 = rt*32 + rr*16 + q*4;
      #pragma unroll
      for (int i=0; i<4; ++i){
        float x = acc[rr][cc][i];
        if (mat == 0){
          const int r = rg0 + i;
          float sk = 0.f;
          if (r < cg) sk = YA[r*128 + cg];
          else if (r > cg) sk = -YA[cg*128 + r];
          x = 0.5f*x + 0.5f*sk;
        }
        Out[(rg0+i)*128 + cg] = x;
      }
    }
  }
}

// ---------------- K4a: CA, CB, Y0 = C X0^T + by, t=0 output, cbx = C bx
__global__ __launch_bounds__(1024) void k_mid(float* __restrict__ ws,
    const float* __restrict__ X0, const float* __restrict__ bx,
    const float* __restrict__ by, float* __restrict__ out)
{
  const int role = blockIdx.x;
  const int tid = threadIdx.x;

  if (role >= 6 && role < 14){   // t=0 output: out[b][0][i] = X0[b][i]
    const int t0 = ((role-6)*1024 + tid) * 8;
    const int bb = t0 >> 7, ii = t0 & 127;
    const f32x4 v0 = *(const f32x4*)(X0 + t0);
    const f32x4 v1 = *(const f32x4*)(X0 + t0 + 4);
    float* dst = out + (size_t)bb*65536 + ii;
    *(f32x4*)dst = v0;
    *(f32x4*)(dst + 4) = v1;
    return;
  }
  if (role == 14){               // cbx = C @ bx
    if (tid < 128){
      const float* Cm = ws + OFF_C;
      float s = 0.f;
      for (int j2=0; j2<128; ++j2) s += Cm[tid*128 + j2]*bx[j2];
      ws[OFF_CBX + tid] = s;
    }
    return;
  }

  const int lane = tid & 63, w = tid >> 6, q = lane >> 4, m16 = lane & 15;
  const int rt = w >> 2, cp = w & 3;
  const float* Cm = ws + OFF_C;

  short8 Ah[2][4], Al[2][4];     // A-op = C rows
  #pragma unroll
  for (int rr=0; rr<2; ++rr){
    const int row = rt*32 + rr*16 + m16;
    #pragma unroll
    for (int c=0; c<4; ++c){
      const float* up = Cm + row*128 + c*32 + q*8;
      const f32x4 u0 = *(const f32x4*)up;
      const f32x4 u1 = *(const f32x4*)(up + 4);
      short8 hh, ll;
      #pragma unroll
      for (int jj=0; jj<4; ++jj){
        unsigned short hb_, lb_;
        split_bf(u0[jj], hb_, lb_); hh[jj]   = (short)hb_; ll[jj]   = (short)lb_;
        split_bf(u1[jj], hb_, lb_); hh[jj+4] = (short)hb_; ll[jj+4] = (short)lb_;
      }
      Ah[rr][c] = hh; Al[rr][c] = ll;
    }
  }
  f32x4 acc[2][2];
  #pragma unroll
  for (int rr=0; rr<2; ++rr)
    #pragma unroll
    for (int cc=0; cc<2; ++cc) acc[rr][cc] = (f32x4){0.f,0.f,0.f,0.f};

  if (role < 2){                 // CA / CB
    const float* Rm = ws + ((role == 0) ? OFF_A : OFF_B);
    #pragma unroll
    for (int cc=0; cc<2; ++cc){
      const int n = cp*32 + cc*16 + m16;
      #pragma unroll
      for (int c=0; c<4; ++c){
        const int k0 = c*32 + q*8;
        short8 bh, bl;
        #pragma unroll
        for (int jj=0; jj<8; ++jj){
          unsigned short hb_, lb_;
          split_bf(Rm[(k0+jj)*128 + n], hb_, lb_);
          bh[jj] = (short)hb_; bl[jj] = (short)lb_;
        }
        #pragma unroll
        for (int rr=0; rr<2; ++rr){
          acc[rr][cc] = mfma16(Ah[rr][c], bh, acc[rr][cc]);
          acc[rr][cc] = mfma16(Al[rr][c], bh, acc[rr][cc]);
          acc[rr][cc] = mfma16(Ah[rr][c], bl, acc[rr][cc]);
        }
      }
    }
    float* Om = ws + ((role == 0) ? OFF_CA : OFF_CB);
    #pragma unroll
    for (int rr=0; rr<2; ++rr){
      #pragma unroll
      for (int cc=0; cc<2; ++cc){
        const int cg  = cp*32 + cc*16 + m16;
        const int rg0 = rt*32 + rr*16 + q*4;
        #pragma unroll
        for (int i=0; i<4; ++i) Om[(rg0+i)*128 + cg] = acc[rr][cc][i];
      }
    }
  } else {                       // Y0 block (128 batch cols per block)
    const int bcolbase = (role - 2) * 128;
    #pragma unroll
    for (int cc=0; cc<2; ++cc){
      const int bcol = bcolbase + cp*32 + cc*16 + m16;
      #pragma unroll
      for (int c=0; c<4; ++c){
        const int k0 = c*32 + q*8;
        const float* xp = X0 + bcol*128 + k0;      // B[k][b] = X0[b][k]
        const f32x4 x0v = *(const f32x4*)xp;
        const f32x4 x1v = *(const f32x4*)(xp + 4);
        short8 bh, bl;
        #pragma unroll
        for (int jj=0; jj<4; ++jj){
          unsigned short hb_, lb_;
          split_bf(x0v[jj], hb_, lb_); bh[jj]   = (short)hb_; bl[jj]   = (short)lb_;
          split_bf(x1v[jj], hb_, lb_); bh[jj+4] = (short)hb_; bl[jj+4] = (short)lb_;
        }
        #pragma unroll
        for (int rr=0; rr<2; ++rr){
          acc[rr][cc] = mfma16(Ah[rr][c], bh, acc[rr][cc]);
          acc[rr][cc] = mfma16(Al[rr][c], bh, acc[rr][cc]);
          acc[rr][cc] = mfma16(Ah[rr][c], bl, acc[rr][cc]);
        }
      }
    }
    float* Y0p = ws + OFF_Y0;
    #pragma unroll
    for (int rr=0; rr<2; ++rr){
      #pragma unroll
      for (int cc=0; cc<2; ++cc){
        const int bcol = bcolbase + cp*32 + cc*16 + m16;
        const int rg0  = rt*32 + rr*16 + q*4;
        #pragma unroll
        for (int i=0; i<4; ++i)
          Y0p[(rg0+i)*512 + bcol] = acc[rr][cc][i] + by[rg0+i];
      }
    }
  }
}

// ---------------- K4b: pack M fragments (fp16), S0, h*b2
__global__ __launch_bounds__(1024) void k_pack(float* __restrict__ ws,
    const float* __restrict__ X0, const float* __restrict__ bx)
{
  const int fid = blockIdx.x*1024 + threadIdx.x;
  unsigned short* Mf = (unsigned short*)(ws + OFF_MF);
  if (fid < 8192){               // M frags: tile w(16 rows), chunk c, lane l
    const int w = fid >> 9, c = (fid >> 6) & 7, l = fid & 63;
    const int q = l >> 4, m16 = l & 15;
    const int row = w*16 + m16;            // 0..255 of M = [[A,B],[CA,CB]]
    const int k0 = c*32 + q*8;             // 0..255
    const float* src;
    if (row < 128) src = (k0 < 128) ? (ws + OFF_A  + row*128 + k0)
                                    : (ws + OFF_B  + row*128 + (k0-128));
    else           src = (k0 < 128) ? (ws + OFF_CA + (row-128)*128 + k0)
                                    : (ws + OFF_CB + (row-128)*128 + (k0-128));
    unsigned short* dh = Mf + (size_t)w*8192 + c*1024 + l*8;
    #pragma unroll
    for (int j=0; j<8; ++j) dh[j] = f2h(src[j]);   // fp16 RNE, single product
  } else if (fid < 40960){       // S0 packed per (wg, tile, lane)
    const int t = fid - 8192;
    const int wg = t >> 10, w = (t >> 6) & 15, l = t & 63;
    const int q = l >> 4, m16 = l & 15;
    const int col = wg*16 + m16;
    const int r0 = w*16 + q*4;
    f32x4 v;
    if (r0 < 128){
      v = *(const f32x4*)(X0 + col*128 + r0);
    } else {
      const float* Y0p = ws + OFF_Y0;
      v[0] = Y0p[(r0-128)*512 + col]; v[1] = Y0p[(r0-127)*512 + col];
      v[2] = Y0p[(r0-126)*512 + col]; v[3] = Y0p[(r0-125)*512 + col];
    }
    *(f32x4*)(ws + OFF_S0P + (size_t)t*4) = v;
  } else {                       // h*b2 packed per (tile, lane)
    const int t2 = fid - 40960;
    const int w = t2 >> 6, l = t2 & 63, q = l >> 4;
    const int r0 = w*16 + q*4;
    f32x4 v;
    #pragma unroll
    for (int i=0; i<4; ++i){
      const int r = r0 + i;
      v[i] = 0.01f * ((r < 128) ? bx[r] : ws[OFF_CBX + (r-128)]);
    }
    *(f32x4*)(ws + OFF_HBP + (size_t)t2*4) = v;
  }
}

// ---------------- K5: 511-step recurrence. 32 WGs x 512 thr (8 waves, 2/SIMD).
// Each wave owns 16 X rows (tile w) AND 16 Y rows (tile 8+w): symmetric waves.
// SINGLE fp16 MFMA per (tile, chunk): 16 MFMAs/wave/step. Even/odd chunk
// accumulator pairs for ILP. Y MFMAs first (Y finish overlaps X MFMAs).
// Raw barrier with lgkm-only drain; global stores ride across steps.
// Loop unrolled x2 so V buffer pointers are compile-time constant.
__global__ __launch_bounds__(512) void k_main(const float* __restrict__ ws,
                                              float* __restrict__ out)
{
  const unsigned short* Mf = (const unsigned short*)(ws + OFF_MF);
  const float* S0p = ws + OFF_S0P;
  const float* hbp = ws + OFF_HBP;

  __shared__ unsigned short Vb[2][16][264];  // V^T (fp16): [buf][col n][row k]

  const int tid = threadIdx.x, lane = tid & 63, w = tid >> 6, wg = blockIdx.x;
  const int q = lane >> 4, m16 = lane & 15;

  // r2=0 -> X tile w (rows 16w..16w+15), r2=1 -> Y tile 8+w
  half8 Mh[2][8];
  #pragma unroll
  for (int r2=0; r2<2; ++r2){
    const unsigned short* bp = Mf + (size_t)(w + 8*r2)*8192 + lane*8;
    #pragma unroll
    for (int c=0; c<8; ++c) Mh[r2][c] = *(const half8*)(bp + c*1024);
  }
  f32x4 S[2], hb[2];
  #pragma unroll
  for (int r2=0; r2<2; ++r2){
    S[r2]  = *(const f32x4*)(S0p + (size_t)((wg*16 + w + 8*r2)*64 + lane)*4);
    hb[r2] = *(const f32x4*)(hbp + (size_t)((w + 8*r2)*64 + lane)*4);
  }
  const int r0x = w*16 + q*4;           // owned X rows (V position = row)
  const int r0y = 128 + w*16 + q*4;     // owned Y rows (V position = 128+row)

  float* op = out + (size_t)(wg*16 + m16)*65536 + r0x;   // + t*128
  *(f32x4*)op = S[0];                   // t = 0 output (S0P X-part == X0)

  { // initial V = [X0_fp16 ; tanh(Y0)_fp16]
    union { _Float16 f[4]; uint2 u; } pk;
    #pragma unroll
    for (int i=0; i<4; ++i) pk.f[i] = (_Float16)S[0][i];
    *(uint2*)&Vb[0][m16][r0x] = pk.u;
    #pragma unroll
    for (int i=0; i<4; ++i) pk.f[i] = (_Float16)tanh_fast(S[1][i]);
    *(uint2*)&Vb[0][m16][r0y] = pk.u;
  }
  asm volatile("s_waitcnt lgkmcnt(0)" ::: "memory");
  __builtin_amdgcn_s_barrier();
  asm volatile("" ::: "memory");

  auto step = [&](const unsigned short (*vs)[264], unsigned short (*vd)[264],
                  int t){
    const unsigned short* vrow = &vs[m16][q*8];
    half8 vf[8];
    #pragma unroll
    for (int c=0; c<8; ++c) vf[c] = *(const half8*)(vrow + c*32);

    // Y tile first (even/odd chunk chains)...
    f32x4 e1 = (f32x4){0.f,0.f,0.f,0.f}, o1 = (f32x4){0.f,0.f,0.f,0.f};
    #pragma unroll
    for (int c=0; c<8; c+=2){
      e1 = mfmah(Mh[1][c],   vf[c],   e1);
      o1 = mfmah(Mh[1][c+1], vf[c+1], o1);
    }
    // ...X tile second; Y finish is independent of these MFMAs.
    f32x4 e0 = (f32x4){0.f,0.f,0.f,0.f}, o0 = (f32x4){0.f,0.f,0.f,0.f};
    #pragma unroll
    for (int c=0; c<8; c+=2){
      e0 = mfmah(Mh[0][c],   vf[c],   e0);
      o0 = mfmah(Mh[0][c+1], vf[c+1], o0);
    }
    { // Y finish: update, tanh, pack fp16, LDS write
      union { _Float16 f[4]; uint2 u; } pk;
      #pragma unroll
      for (int i=0; i<4; ++i){
        S[1][i] += 0.01f*(e1[i] + o1[i]) + hb[1][i];
        pk.f[i] = (_Float16)tanh_fast(S[1][i]);
      }
      *(uint2*)&vd[m16][r0y] = pk.u;
    }
    { // X finish: update, pack fp16, LDS write
      union { _Float16 f[4]; uint2 u; } pk;
      #pragma unroll
      for (int i=0; i<4; ++i){
        S[0][i] += 0.01f*(e0[i] + o0[i]) + hb[0][i];
        pk.f[i] = (_Float16)S[0][i];
      }
      *(uint2*)&vd[m16][r0x] = pk.u;
    }
    // raw barrier: drain LDS writes only; global stores stay in flight.
    asm volatile("s_waitcnt lgkmcnt(0)" ::: "memory");
    __builtin_amdgcn_s_barrier();
    asm volatile("" ::: "memory");
    // X fp32 store after the barrier: overlaps next step's LDS reads/MFMAs.
    *(f32x4*)(op + (size_t)t*128) = S[0];
  };

  for (int t = 1; t < 511; t += 2){      // 255 double-steps: buf0->1, buf1->0
    step(Vb[0], Vb[1], t);
    step(Vb[1], Vb[0], t + 1);
  }
  step(Vb[0], Vb[1], 511);               // final step
}

extern "C" void kernel_launch(void* const* d_in, const int* in_sizes, int n_in,
                              void* d_out, int out_size, void* d_ws, size_t ws_size,
                              hipStream_t stream)
{
  (void)in_sizes; (void)n_in; (void)out_size; (void)ws_size;
  const float* X0  = (const float*)d_in[0];
  const float* GA1 = (const float*)d_in[1];
  const float* GAk = (const float*)d_in[2];
  const float* GAp = (const float*)d_in[3];
  const float* YA  = (const float*)d_in[4];
  const float* UA  = (const float*)d_in[5];
  const float* UB  = (const float*)d_in[6];
  const float* VB  = (const float*)d_in[7];
  const float* SBm = (const float*)d_in[8];
  const float* UC  = (const float*)d_in[9];
  const float* VC  = (const float*)d_in[10];
  const float* SCm = (const float*)d_in[11];
  const float* bx  = (const float*)d_in[12];
  const float* by  = (const float*)d_in[13];
  float* out = (float*)d_out;
  float* ws  = (float*)d_ws;

  k_expm<<<dim3(5),  dim3(1024), 0, stream>>>(UA, UB, VB, UC, VC, ws);
  k_abc <<<dim3(3),  dim3(1024), 0, stream>>>(ws, SBm, SCm, GA1, GAk, GAp, YA);
  k_mid <<<dim3(15), dim3(1024), 0, stream>>>(ws, X0, bx, by, out);
  k_pack<<<dim3(41), dim3(1024), 0, stream>>>(ws, X0, bx);
  k_main<<<dim3(32), dim3(512),  0, stream>>>(ws, out);
}